// Round 2
// baseline (240.520 us; speedup 1.0000x reference)
//
#include <hip/hip_runtime.h>

#define DIM 64
#define HID 512
#define BATCH 8192
#define SB 8     // samples per block
#define NT 512   // threads per block (one hidden column each)

// P[j][k] = W2[j][k] * sum_i W1[i][j] * W3[k][i]   (512x512), sample-independent
__global__ __launch_bounds__(256) void compute_P(const float* __restrict__ W1,
                                                 const float* __restrict__ W2,
                                                 const float* __restrict__ W3,
                                                 float* __restrict__ P) {
    int idx = blockIdx.x * 256 + threadIdx.x;   // 512*512 elements
    int k = idx & (HID - 1);
    int j = idx >> 9;
    float acc = 0.f;
#pragma unroll
    for (int i = 0; i < DIM; ++i) {
        acc = fmaf(W1[i * HID + j], W3[k * DIM + i], acc);
    }
    P[j * HID + k] = W2[j * HID + k] * acc;
}

__global__ __launch_bounds__(NT, 8) void fused_main(
        const float* __restrict__ t,
        const float* __restrict__ x,
        const float* __restrict__ W1, const float* __restrict__ b1,
        const float* __restrict__ W2, const float* __restrict__ b2,
        const float* __restrict__ W3, const float* __restrict__ b3,
        const float* __restrict__ P, float* __restrict__ out) {
    __shared__ float xs[SB][DIM + 1];
    __shared__ float h1s[SB][HID];   // h1, later reused for h2
    __shared__ float d1s[SB][HID];   // 1 - h1^2
    __shared__ float wred[8][SB];

    const int tid = threadIdx.x;
    const int s0 = blockIdx.x * SB;

    // ---- load x tile (+ t as the 65th feature) ----
    if (tid < SB * DIM) {
        int s = tid >> 6, i = tid & 63;
        xs[s][i] = x[(s0 + s) * DIM + i];
    }
    if (tid < SB) xs[tid][DIM] = t[0];
    __syncthreads();

    const int k = tid;   // this thread's hidden column

    // ---- phase 1: z1 = [x,t] @ W1 + b1 ; h1 = tanh(z1), d1 = 1-h1^2 ----
    float za[SB];
    {
        float bk = b1[k];
#pragma unroll
        for (int s = 0; s < SB; ++s) za[s] = bk;
    }
    for (int i = 0; i <= DIM; ++i) {
        float w = W1[i * HID + k];
#pragma unroll
        for (int s = 0; s < SB; ++s) za[s] = fmaf(xs[s][i], w, za[s]);
    }
#pragma unroll
    for (int s = 0; s < SB; ++s) {
        float h = tanhf(za[s]);
        h1s[s][k] = h;
        d1s[s][k] = fmaf(-h, h, 1.0f);
    }
    __syncthreads();

    // ---- phase 2: z2 = h1 @ W2 + b2  and  srow = d1 @ P  (fused) ----
    float sa[SB];
    {
        float bk = b2[k];
#pragma unroll
        for (int s = 0; s < SB; ++s) { za[s] = bk; sa[s] = 0.f; }
    }
    for (int j = 0; j < HID; j += 4) {
        float w20 = W2[(j + 0) * HID + k];
        float w21 = W2[(j + 1) * HID + k];
        float w22 = W2[(j + 2) * HID + k];
        float w23 = W2[(j + 3) * HID + k];
        float p0 = P[(j + 0) * HID + k];
        float p1 = P[(j + 1) * HID + k];
        float p2 = P[(j + 2) * HID + k];
        float p3 = P[(j + 3) * HID + k];
#pragma unroll
        for (int s = 0; s < SB; ++s) {
            float4 h4 = *(const float4*)&h1s[s][j];   // broadcast
            float4 d4 = *(const float4*)&d1s[s][j];   // broadcast
            float z = za[s], sv = sa[s];
            z = fmaf(h4.x, w20, z);
            z = fmaf(h4.y, w21, z);
            z = fmaf(h4.z, w22, z);
            z = fmaf(h4.w, w23, z);
            sv = fmaf(d4.x, p0, sv);
            sv = fmaf(d4.y, p1, sv);
            sv = fmaf(d4.z, p2, sv);
            sv = fmaf(d4.w, p3, sv);
            za[s] = z; sa[s] = sv;
        }
    }

    // ---- h2, d2, per-thread divergence partial (column k) ----
    float divp[SB];
#pragma unroll
    for (int s = 0; s < SB; ++s) {
        float h2 = tanhf(za[s]);
        float d2 = fmaf(-h2, h2, 1.0f);
        divp[s] = sa[s] * d2;
        za[s] = h2;
    }
    __syncthreads();   // all phase-2 LDS reads done
#pragma unroll
    for (int s = 0; s < SB; ++s) h1s[s][k] = za[s];   // store h2

    // ---- divergence reduction: wave shuffle, then cross-wave via LDS ----
#pragma unroll
    for (int s = 0; s < SB; ++s) {
        float v = divp[s];
#pragma unroll
        for (int off = 32; off > 0; off >>= 1) v += __shfl_xor(v, off, 64);
        if ((tid & 63) == 0) wred[tid >> 6][s] = v;
    }
    __syncthreads();   // covers h2 writes + wred writes
    if (tid < SB) {
        float d = 0.f;
#pragma unroll
        for (int w = 0; w < 8; ++w) d += wred[w][tid];
        out[BATCH * DIM + s0 + tid] = -d;
    }

    // ---- phase 3: v = h2 @ W3 + b3 (one sample per wave) ----
    const int o = tid & 63, s = tid >> 6;
    float acc = b3[o];
    for (int kk = 0; kk < HID; kk += 4) {
        float4 h4 = *(const float4*)&h1s[s][kk];   // broadcast within wave
        acc = fmaf(h4.x, W3[(kk + 0) * DIM + o], acc);
        acc = fmaf(h4.y, W3[(kk + 1) * DIM + o], acc);
        acc = fmaf(h4.z, W3[(kk + 2) * DIM + o], acc);
        acc = fmaf(h4.w, W3[(kk + 3) * DIM + o], acc);
    }
    out[(s0 + s) * DIM + o] = acc;
}

extern "C" void kernel_launch(void* const* d_in, const int* in_sizes, int n_in,
                              void* d_out, int out_size, void* d_ws, size_t ws_size,
                              hipStream_t stream) {
    const float* t  = (const float*)d_in[0];
    const float* x  = (const float*)d_in[1];
    const float* W1 = (const float*)d_in[2];
    const float* b1 = (const float*)d_in[3];
    const float* W2 = (const float*)d_in[4];
    const float* b2 = (const float*)d_in[5];
    const float* W3 = (const float*)d_in[6];
    const float* b3 = (const float*)d_in[7];
    float* out = (float*)d_out;
    float* P   = (float*)d_ws;   // 512*512*4 = 1 MB

    compute_P<<<(HID * HID) / 256, 256, 0, stream>>>(W1, W2, W3, P);
    fused_main<<<BATCH / SB, NT, 0, stream>>>(t, x, W1, b1, W2, b2, W3, b3, P, out);
}

// Round 3
// 60.398 us; speedup vs baseline: 3.9823x; 3.9823x over previous
//
#include <hip/hip_runtime.h>

#define DIM 64
#define HID 512
#define BATCH 8192
#define MB 16            // samples per block (one MFMA row-tile)

typedef __attribute__((ext_vector_type(8))) short short8;
typedef __attribute__((ext_vector_type(4))) float f32x4;
typedef float float4_ __attribute__((ext_vector_type(4)));

__device__ __forceinline__ unsigned short f2bf(float f) {
    union { float f; unsigned u; } v; v.f = f;
    return (unsigned short)((v.u + 0x7FFFu + ((v.u >> 16) & 1u)) >> 16);
}

// P[j][k] = W2[j][k] * sum_i W1[i][j] * W3[k][i]   (512x512, fp32)
__global__ __launch_bounds__(256) void compute_P(const float* __restrict__ W1,
                                                 const float* __restrict__ W2,
                                                 const float* __restrict__ W3,
                                                 float* __restrict__ P) {
    int idx = blockIdx.x * 256 + threadIdx.x;
    int k = idx & (HID - 1);
    int j = idx >> 9;
    float acc = 0.f;
#pragma unroll
    for (int i = 0; i < DIM; ++i) acc = fmaf(W1[i * HID + j], W3[k * DIM + i], acc);
    P[j * HID + k] = W2[j * HID + k] * acc;
}

// Pack W2, P, W3 into bf16 MFMA-B fragments.
// Fragment (ntile, kstep): lane l, elem e  <-  src[(kstep*32 + (l>>4)*8 + e)*N + ntile*16 + (l&15)]
// Stored at dst[(fragIdx*64 + l)*8 + e]  -> main kernel loads one coalesced 16B per lane.
__global__ __launch_bounds__(256) void pack_frags(const float* __restrict__ W2,
                                                  const float* __restrict__ W3,
                                                  const float* __restrict__ P,
                                                  unsigned short* __restrict__ w2pk,
                                                  unsigned short* __restrict__ ppk,
                                                  unsigned short* __restrict__ w3pk) {
    int gid = blockIdx.x * 256 + threadIdx.x;   // 1088 frags * 64 lanes
    int f = gid >> 6;
    int l = gid & 63;
    const float* src; unsigned short* dst; int N, fi;
    if (f < 512)       { src = W2; dst = w2pk; fi = f;        N = HID; }
    else if (f < 1024) { src = P;  dst = ppk;  fi = f - 512;  N = HID; }
    else               { src = W3; dst = w3pk; fi = f - 1024; N = DIM; }
    int ntile = fi >> 4, kstep = fi & 15;
    int n  = ntile * 16 + (l & 15);
    int kb = kstep * 32 + (l >> 4) * 8;
    unsigned short* o = dst + ((size_t)(fi * 64 + l)) * 8;
#pragma unroll
    for (int e = 0; e < 8; ++e) o[e] = f2bf(src[(size_t)(kb + e) * N + n]);
}

__global__ __launch_bounds__(256) void fused_main(
        const float* __restrict__ t, const float* __restrict__ x,
        const float* __restrict__ W1, const float* __restrict__ b1,
        const float* __restrict__ b2, const float* __restrict__ b3,
        const unsigned short* __restrict__ w2pk,
        const unsigned short* __restrict__ ppk,
        const unsigned short* __restrict__ w3pk,
        float* __restrict__ out) {
    __shared__ float xs[MB * DIM];
    __shared__ unsigned short h1s[MB * HID];   // bf16, XOR-swizzled rows
    __shared__ unsigned short d1s[MB * HID];
    __shared__ unsigned short h2s[MB * HID];
    __shared__ float wred[4][MB];

    const int tid = threadIdx.x;
    const int s0 = blockIdx.x * MB;

    // ---- stage x tile (1024 floats = 256 float4, one per thread) ----
    ((float4_*)xs)[tid] = ((const float4_*)(x + (size_t)s0 * DIM))[tid];
    __syncthreads();

    // ---- phase 1 (VALU, K=64 too small for MFMA): h1 = tanh([x,t]@W1+b1), d1 = 1-h1^2 ----
    const int k0 = tid, k1 = tid + 256;
    const float tv = t[0];
    float za[MB], zb[MB];
    {
        float ia = fmaf(tv, W1[DIM * HID + k0], b1[k0]);   // fold t-row + bias
        float ib = fmaf(tv, W1[DIM * HID + k1], b1[k1]);
#pragma unroll
        for (int s = 0; s < MB; ++s) { za[s] = ia; zb[s] = ib; }
    }
    for (int i = 0; i < DIM; i += 4) {
        float wa0 = W1[(i+0)*HID + k0], wa1 = W1[(i+1)*HID + k0];
        float wa2 = W1[(i+2)*HID + k0], wa3 = W1[(i+3)*HID + k0];
        float wb0 = W1[(i+0)*HID + k1], wb1 = W1[(i+1)*HID + k1];
        float wb2 = W1[(i+2)*HID + k1], wb3 = W1[(i+3)*HID + k1];
#pragma unroll
        for (int s = 0; s < MB; ++s) {
            float4_ x4 = *(const float4_*)&xs[s * DIM + i];
            float a = za[s], b = zb[s];
            a = fmaf(x4.x, wa0, a); b = fmaf(x4.x, wb0, b);
            a = fmaf(x4.y, wa1, a); b = fmaf(x4.y, wb1, b);
            a = fmaf(x4.z, wa2, a); b = fmaf(x4.z, wb2, b);
            a = fmaf(x4.w, wa3, a); b = fmaf(x4.w, wb3, b);
            za[s] = a; zb[s] = b;
        }
    }
#pragma unroll
    for (int s = 0; s < MB; ++s) {
        float ha = tanhf(za[s]), hb = tanhf(zb[s]);
        int a0 = ((s * HID + k0) * 2) ^ ((s & 7) << 4);    // XOR-swizzle (G4)
        int a1 = ((s * HID + k1) * 2) ^ ((s & 7) << 4);
        *(unsigned short*)((char*)h1s + a0) = f2bf(ha);
        *(unsigned short*)((char*)h1s + a1) = f2bf(hb);
        *(unsigned short*)((char*)d1s + a0) = f2bf(fmaf(-ha, ha, 1.f));
        *(unsigned short*)((char*)d1s + a1) = f2bf(fmaf(-hb, hb, 1.f));
    }
    __syncthreads();

    // ---- phase 2 (MFMA): z2 = h1@W2 (+b2), srow = d1@P ; div = sum srow*d2 ----
    const int wv = tid >> 6;        // wave 0..3, owns ntiles wv*8 .. wv*8+7
    const int l  = tid & 63;
    const int g  = l >> 4;          // lane group
    const int lr = l & 15;          // A-row / B-col within tile
    const int abase = lr * (HID * 2) + g * 16;   // A-frag byte addr before kstep/swizzle
    const int aswz  = (lr & 7) << 4;

    float divp[4] = {0.f, 0.f, 0.f, 0.f};

    for (int nt = 0; nt < 8; ++nt) {
        const int n = wv * 8 + nt;
        f32x4 zacc = {0.f, 0.f, 0.f, 0.f}, sacc = {0.f, 0.f, 0.f, 0.f};
        const short8* bw = (const short8*)w2pk + (size_t)(n * 16) * 64 + l;
        const short8* bp = (const short8*)ppk  + (size_t)(n * 16) * 64 + l;
#pragma unroll
        for (int ks = 0; ks < 16; ++ks) {
            int aoff = (abase + ks * 64) ^ aswz;
            short8 ah = *(const short8*)((const char*)h1s + aoff);
            short8 ad = *(const short8*)((const char*)d1s + aoff);
            short8 bwv = bw[ks * 64];
            short8 bpv = bp[ks * 64];
            zacc = __builtin_amdgcn_mfma_f32_16x16x32_bf16(ah, bwv, zacc, 0, 0, 0);
            sacc = __builtin_amdgcn_mfma_f32_16x16x32_bf16(ad, bpv, sacc, 0, 0, 0);
        }
        const int c = n * 16 + lr;
        const float b2v = b2[c];
#pragma unroll
        for (int r = 0; r < 4; ++r) {
            int row = g * 4 + r;
            float h2 = tanhf(zacc[r] + b2v);
            float d2 = fmaf(-h2, h2, 1.f);
            divp[r] = fmaf(sacc[r], d2, divp[r]);
            int ao = ((row * HID + c) * 2) ^ ((row & 7) << 4);
            *(unsigned short*)((char*)h2s + ao) = f2bf(h2);
        }
    }

    // ---- divergence: reduce cols within 16-lane group, then cross-wave via LDS ----
#pragma unroll
    for (int off = 1; off < 16; off <<= 1) {
#pragma unroll
        for (int r = 0; r < 4; ++r) divp[r] += __shfl_xor(divp[r], off, 64);
    }
    if (lr == 0) {
#pragma unroll
        for (int r = 0; r < 4; ++r) wred[wv][g * 4 + r] = divp[r];
    }
    __syncthreads();   // covers h2s writes + wred
    if (tid < MB) {
        float d = wred[0][tid] + wred[1][tid] + wred[2][tid] + wred[3][tid];
        out[(size_t)BATCH * DIM + s0 + tid] = -d;
    }

    // ---- phase 3 (MFMA): v = h2 @ W3 + b3 ; wave wv owns ntile wv ----
    {
        const int n = wv;
        f32x4 acc = {0.f, 0.f, 0.f, 0.f};
        const short8* bw = (const short8*)w3pk + (size_t)(n * 16) * 64 + l;
#pragma unroll
        for (int ks = 0; ks < 16; ++ks) {
            int aoff = (abase + ks * 64) ^ aswz;
            short8 ah = *(const short8*)((const char*)h2s + aoff);
            short8 bv = bw[ks * 64];
            acc = __builtin_amdgcn_mfma_f32_16x16x32_bf16(ah, bv, acc, 0, 0, 0);
        }
        const int c = n * 16 + lr;
        const float b3v = b3[c];
#pragma unroll
        for (int r = 0; r < 4; ++r) {
            int row = g * 4 + r;
            out[(size_t)(s0 + row) * DIM + c] = acc[r] + b3v;
        }
    }
}

extern "C" void kernel_launch(void* const* d_in, const int* in_sizes, int n_in,
                              void* d_out, int out_size, void* d_ws, size_t ws_size,
                              hipStream_t stream) {
    const float* t  = (const float*)d_in[0];
    const float* x  = (const float*)d_in[1];
    const float* W1 = (const float*)d_in[2];
    const float* b1 = (const float*)d_in[3];
    const float* W2 = (const float*)d_in[4];
    const float* b2 = (const float*)d_in[5];
    const float* W3 = (const float*)d_in[6];
    const float* b3 = (const float*)d_in[7];
    float* out = (float*)d_out;

    float*          P    = (float*)d_ws;                                   // 1 MB fp32
    unsigned short* w2pk = (unsigned short*)((char*)d_ws + (1 << 20));     // 512 KB
    unsigned short* ppk  = (unsigned short*)((char*)d_ws + (1 << 20) + (512 << 10)); // 512 KB
    unsigned short* w3pk = (unsigned short*)((char*)d_ws + (2 << 20));     // 64 KB

    compute_P<<<(HID * HID) / 256, 256, 0, stream>>>(W1, W2, W3, P);
    pack_frags<<<(1088 * 64) / 256, 256, 0, stream>>>(W2, W3, P, w2pk, ppk, w3pk);
    fused_main<<<BATCH / MB, 256, 0, stream>>>(t, x, W1, b1, b2, b3, w2pk, ppk, w3pk, out);
}

// Round 4
// 40.331 us; speedup vs baseline: 5.9636x; 1.4975x over previous
//
#include <hip/hip_runtime.h>

#define DIM 64
#define HID 512
#define BATCH 8192
#define MB 32     // samples per block
#define NTHR 512  // 8 waves: 2 M-tiles x 4 N-quarters

typedef __attribute__((ext_vector_type(8))) short short8;
typedef __attribute__((ext_vector_type(4))) float f32x4;
typedef float float4_ __attribute__((ext_vector_type(4)));

__device__ __forceinline__ unsigned short f2bf(float f) {
    union { float f; unsigned u; } v; v.f = f;
    return (unsigned short)((v.u + 0x7FFFu + ((v.u >> 16) & 1u)) >> 16);
}
__device__ __forceinline__ float tanh_fast(float x) {
    float e = __expf(2.f * x);
    return 1.f - __fdividef(2.f, e + 1.f);
}

// MT[k][j] = sum_i W1[i][j] * W3[k][i]   (fp32, [512][512]) — fully coalesced
__global__ __launch_bounds__(256) void compute_MT(const float* __restrict__ W1,
                                                  const float* __restrict__ W3,
                                                  float* __restrict__ MT) {
    int j  = ((blockIdx.x & 1) << 8) + threadIdx.x;   // 0..511, lane-contiguous
    int ka = blockIdx.x >> 1;                         // 0..255, block-uniform
    int kb = ka + 256;
    float aa = 0.f, ab = 0.f;
#pragma unroll
    for (int i = 0; i < DIM; ++i) {
        float w1 = W1[i * HID + j];
        aa = fmaf(w1, W3[ka * DIM + i], aa);
        ab = fmaf(w1, W3[kb * DIM + i], ab);
    }
    MT[(size_t)ka * HID + j] = aa;
    MT[(size_t)kb * HID + j] = ab;
}

// Pack B-matrices into bf16 MFMA fragments + compute c1 = b1 + t*W1[64,:].
// frag fi, lane l, elem e <- src[(kb+e)*N + n],  n = ntile*16 + (l&15),
// kb = kstep*32 + (l>>4)*8 ; stored at dst[(fi*64+l)*8 + e].
__global__ __launch_bounds__(256) void pack_frags(
        const float* __restrict__ t,  const float* __restrict__ W1,
        const float* __restrict__ b1, const float* __restrict__ W2,
        const float* __restrict__ W3, const float* __restrict__ MT,
        unsigned short* __restrict__ w2pk, unsigned short* __restrict__ ppk,
        unsigned short* __restrict__ w3pk, unsigned short* __restrict__ w1pk,
        float* __restrict__ c1) {
    int b = blockIdx.x;
    if (b >= 288) {           // c1 tail: 2 blocks x 256 threads
        int n = (b - 288) * 256 + threadIdx.x;
        c1[n] = fmaf(t[0], W1[DIM * HID + n], b1[n]);
        return;
    }
    int gid = b * 256 + threadIdx.x;
    int f = gid >> 6, l = gid & 63;
    if (f < 512) {            // W2: fi = nt*16 + ks, N=512
        int fi = f, n = (fi >> 4) * 16 + (l & 15), kb = (fi & 15) * 32 + (l >> 4) * 8;
        unsigned short* o = w2pk + ((size_t)(fi * 64 + l)) * 8;
#pragma unroll
        for (int e = 0; e < 8; ++e) o[e] = f2bf(W2[(size_t)(kb + e) * HID + n]);
    } else if (f < 1024) {    // P = W2 .* M : read MT[n][kb+e] * W2[(kb+e)][n]
        int fi = f - 512, n = (fi >> 4) * 16 + (l & 15), kb = (fi & 15) * 32 + (l >> 4) * 8;
        unsigned short* o = ppk + ((size_t)(fi * 64 + l)) * 8;
#pragma unroll
        for (int e = 0; e < 8; ++e)
            o[e] = f2bf(MT[(size_t)n * HID + kb + e] * W2[(size_t)(kb + e) * HID + n]);
    } else if (f < 1088) {    // W3: fi = nt*16 + ks, N=64
        int fi = f - 1024, n = (fi >> 4) * 16 + (l & 15), kb = (fi & 15) * 32 + (l >> 4) * 8;
        unsigned short* o = w3pk + ((size_t)(fi * 64 + l)) * 8;
#pragma unroll
        for (int e = 0; e < 8; ++e) o[e] = f2bf(W3[(size_t)(kb + e) * DIM + n]);
    } else {                  // W1 (first 64 rows): fi = nt*2 + ks, N=512
        int fi = f - 1088, n = (fi >> 1) * 16 + (l & 15), kb = (fi & 1) * 32 + (l >> 4) * 8;
        unsigned short* o = w1pk + ((size_t)(fi * 64 + l)) * 8;
#pragma unroll
        for (int e = 0; e < 8; ++e) o[e] = f2bf(W1[(size_t)(kb + e) * HID + n]);
    }
}

// LDS A-tile addressing: [mt][ks][row 16][kw 32] bf16, row pitch 64B,
// byte ^= (row&7)<<4  (2-way max on read/write = free)
__device__ __forceinline__ int afrag_addr(int mt, int ks, int row, int kwbyte) {
    return ((((mt * 16 + ks) * 16 + row) * 64) + kwbyte) ^ ((row & 7) << 4);
}

__global__ __launch_bounds__(NTHR, 2) void fused_main(
        const float* __restrict__ x,  const float* __restrict__ c1,
        const float* __restrict__ b2, const float* __restrict__ b3,
        const unsigned short* __restrict__ w1pk, const unsigned short* __restrict__ w2pk,
        const unsigned short* __restrict__ ppk,  const unsigned short* __restrict__ w3pk,
        float* __restrict__ out) {
    __shared__ unsigned short h1s[MB * HID];   // 32 KB, frag-layout
    __shared__ unsigned short d1s[MB * HID];   // 32 KB
    __shared__ unsigned short h2s[MB * HID];   // 32 KB
    __shared__ float wred[4][MB];

    const int tid = threadIdx.x;
    const int wave = tid >> 6;
    const int wm = wave & 1;        // M-tile 0/1
    const int wn = wave >> 1;       // N-quarter 0..3
    const int l = tid & 63;
    const int g = l >> 4, lr = l & 15;
    const int s0 = blockIdx.x * MB;

    // ======== phase 1 (MFMA): h1 = tanh(x @ W1[0:64] + c1), d1 = 1-h1^2 ========
    union U8 { short8 s8; unsigned short u[8]; };
    short8 ax[2];
#pragma unroll
    for (int ks = 0; ks < 2; ++ks) {
        const float* xp = x + (size_t)(s0 + wm * 16 + lr) * DIM + ks * 32 + g * 8;
        float4_ x0 = *(const float4_*)xp;
        float4_ x1 = *(const float4_*)(xp + 4);
        U8 u;
        u.u[0] = f2bf(x0.x); u.u[1] = f2bf(x0.y); u.u[2] = f2bf(x0.z); u.u[3] = f2bf(x0.w);
        u.u[4] = f2bf(x1.x); u.u[5] = f2bf(x1.y); u.u[6] = f2bf(x1.z); u.u[7] = f2bf(x1.w);
        ax[ks] = u.s8;
    }
    {
        f32x4 acc1[8];
#pragma unroll
        for (int nt = 0; nt < 8; ++nt) {
            int ntg = wn * 8 + nt;
            const short8* bw = (const short8*)w1pk + (size_t)(ntg * 2) * 64 + l;
            f32x4 a = {0.f, 0.f, 0.f, 0.f};
            a = __builtin_amdgcn_mfma_f32_16x16x32_bf16(ax[0], bw[0],  a, 0, 0, 0);
            a = __builtin_amdgcn_mfma_f32_16x16x32_bf16(ax[1], bw[64], a, 0, 0, 0);
            acc1[nt] = a;
        }
#pragma unroll
        for (int nt = 0; nt < 8; ++nt) {
            int c = (wn * 8 + nt) * 16 + lr;
            float c1v = c1[c];
            int ks = c >> 5, kwb = (c & 31) * 2;
#pragma unroll
            for (int r = 0; r < 4; ++r) {
                int row = g * 4 + r;
                float h = tanh_fast(acc1[nt][r] + c1v);
                float d = fmaf(-h, h, 1.f);
                int a0 = afrag_addr(wm, ks, row, kwb);
                *(unsigned short*)((char*)h1s + a0) = f2bf(h);
                *(unsigned short*)((char*)d1s + a0) = f2bf(d);
            }
        }
    }
    __syncthreads();

    // ======== phase 2 (MFMA): z2 = h1@W2+b2, srow = d1@P, div partials ========
    short8 ah[16], ad[16];
#pragma unroll
    for (int ks = 0; ks < 16; ++ks) {
        int a0 = afrag_addr(wm, ks, lr, g * 16);
        ah[ks] = *(const short8*)((const char*)h1s + a0);
        ad[ks] = *(const short8*)((const char*)d1s + a0);
    }
    float divp[4] = {0.f, 0.f, 0.f, 0.f};
#pragma unroll 1
    for (int nt = 0; nt < 8; ++nt) {
        int ntg = wn * 8 + nt;
        const short8* bw = (const short8*)w2pk + (size_t)(ntg * 16) * 64 + l;
        const short8* bp = (const short8*)ppk  + (size_t)(ntg * 16) * 64 + l;
        f32x4 zacc = {0.f, 0.f, 0.f, 0.f}, sacc = {0.f, 0.f, 0.f, 0.f};
#pragma unroll
        for (int ks = 0; ks < 16; ++ks) {
            zacc = __builtin_amdgcn_mfma_f32_16x16x32_bf16(ah[ks], bw[ks * 64], zacc, 0, 0, 0);
            sacc = __builtin_amdgcn_mfma_f32_16x16x32_bf16(ad[ks], bp[ks * 64], sacc, 0, 0, 0);
        }
        int c = ntg * 16 + lr;
        float b2v = b2[c];
        int ks2 = c >> 5, kwb = (c & 31) * 2;
#pragma unroll
        for (int r = 0; r < 4; ++r) {
            int row = g * 4 + r;
            float h2 = tanh_fast(zacc[r] + b2v);
            float d2 = fmaf(-h2, h2, 1.f);
            divp[r] = fmaf(sacc[r], d2, divp[r]);
            *(unsigned short*)((char*)h2s + afrag_addr(wm, ks2, row, kwb)) = f2bf(h2);
        }
    }

    // divergence: reduce over 16 cols (lr) then over 4 wn-waves via LDS
#pragma unroll
    for (int off = 1; off < 16; off <<= 1) {
#pragma unroll
        for (int r = 0; r < 4; ++r) divp[r] += __shfl_xor(divp[r], off, 64);
    }
    if (lr == 0) {
#pragma unroll
        for (int r = 0; r < 4; ++r) wred[wn][wm * 16 + g * 4 + r] = divp[r];
    }
    __syncthreads();   // covers h2s + wred
    if (tid < MB) {
        float d = wred[0][tid] + wred[1][tid] + wred[2][tid] + wred[3][tid];
        out[(size_t)BATCH * DIM + s0 + tid] = -d;
    }

    // ======== phase 3 (MFMA): v = h2 @ W3 + b3 ; wave (wm,wn) -> ntile wn ========
    {
        short8 a2[16];
#pragma unroll
        for (int ks = 0; ks < 16; ++ks)
            a2[ks] = *(const short8*)((const char*)h2s + afrag_addr(wm, ks, lr, g * 16));
        f32x4 acc = {0.f, 0.f, 0.f, 0.f};
        const short8* bw = (const short8*)w3pk + (size_t)(wn * 16) * 64 + l;
#pragma unroll
        for (int ks = 0; ks < 16; ++ks)
            acc = __builtin_amdgcn_mfma_f32_16x16x32_bf16(a2[ks], bw[ks * 64], acc, 0, 0, 0);
        int c = wn * 16 + lr;
        float b3v = b3[c];
#pragma unroll
        for (int r = 0; r < 4; ++r)
            out[(size_t)(s0 + wm * 16 + g * 4 + r) * DIM + c] = acc[r] + b3v;
    }
}

extern "C" void kernel_launch(void* const* d_in, const int* in_sizes, int n_in,
                              void* d_out, int out_size, void* d_ws, size_t ws_size,
                              hipStream_t stream) {
    const float* t  = (const float*)d_in[0];
    const float* x  = (const float*)d_in[1];
    const float* W1 = (const float*)d_in[2];
    const float* b1 = (const float*)d_in[3];
    const float* W2 = (const float*)d_in[4];
    const float* b2 = (const float*)d_in[5];
    const float* W3 = (const float*)d_in[6];
    const float* b3 = (const float*)d_in[7];
    float* out = (float*)d_out;

    char* ws = (char*)d_ws;
    float*          MT   = (float*)ws;                              // 1 MB
    unsigned short* w2pk = (unsigned short*)(ws + (1 << 20));       // 512 KB
    unsigned short* ppk  = (unsigned short*)(ws + (1 << 20) + (512 << 10)); // 512 KB
    unsigned short* w3pk = (unsigned short*)(ws + (2 << 20));       // 64 KB
    unsigned short* w1pk = (unsigned short*)(ws + (2 << 20) + (64 << 10));  // 64 KB
    float*          c1   = (float*)(ws + (2 << 20) + (128 << 10));  // 2 KB

    compute_MT<<<512, 256, 0, stream>>>(W1, W3, MT);
    pack_frags<<<290, 256, 0, stream>>>(t, W1, b1, W2, W3, MT, w2pk, ppk, w3pk, w1pk, c1);
    fused_main<<<BATCH / MB, NTHR, 0, stream>>>(x, c1, b2, b3, w1pk, w2pk, ppk, w3pk, out);
}

// Round 6
// 36.947 us; speedup vs baseline: 6.5098x; 1.0916x over previous
//
#include <hip/hip_runtime.h>

#define DIM 64
#define HID 512
#define BATCH 8192
#define MB 32     // samples per block (one 32-row M-supertile)
#define NTHR 512  // 8 waves

typedef __attribute__((ext_vector_type(8))) short short8;
typedef __attribute__((ext_vector_type(4))) float f32x4;
typedef __attribute__((ext_vector_type(16))) float f32x16;
typedef float float4_ __attribute__((ext_vector_type(4)));

#define Z16 {0.f,0.f,0.f,0.f,0.f,0.f,0.f,0.f,0.f,0.f,0.f,0.f,0.f,0.f,0.f,0.f}

__device__ __forceinline__ unsigned short f2bf(float f) {
    union { float f; unsigned u; } v; v.f = f;
    return (unsigned short)((v.u + 0x7FFFu + ((v.u >> 16) & 1u)) >> 16);
}
__device__ __forceinline__ float tanh_fast(float x) {
    float e = __expf(2.f * x);
    return 1.f - __fdividef(2.f, e + 1.f);
}

// One prep kernel: packs W2,P,W3,W1 into bf16 MFMA-B fragments (P's M-factor
// computed on the fly) + c1 = b1 + t*W1[64,:].
// 32-col frags (W2,P):  frag fi=nt*32+ks: lane l,e -> src[k*512+n],
//   n = nt*32+(l&31), k = ks*16+(l>>5)*8+e.   512 frags each.
// 16-col frags (W3,W1): n = nt*16+(l&15), k = ks*32+(l>>4)*8+e.
__global__ __launch_bounds__(256) void prep(
        const float* __restrict__ t,  const float* __restrict__ W1,
        const float* __restrict__ b1, const float* __restrict__ W2,
        const float* __restrict__ W3,
        unsigned short* __restrict__ w2pk, unsigned short* __restrict__ ppk,
        unsigned short* __restrict__ w3pk, unsigned short* __restrict__ w1pk,
        float* __restrict__ c1) {
    int b = blockIdx.x;
    if (b >= 288) {   // c1 tail
        int n = (b - 288) * 256 + threadIdx.x;
        c1[n] = fmaf(t[0], W1[DIM * HID + n], b1[n]);
        return;
    }
    int gid = b * 256 + threadIdx.x;
    int f = gid >> 6, l = gid & 63;
    if (f < 512) {            // W2
        int nt = f >> 5, ks = f & 31;
        int n = nt * 32 + (l & 31), k0 = ks * 16 + (l >> 5) * 8;
        unsigned short* o = w2pk + (size_t)(f * 64 + l) * 8;
#pragma unroll
        for (int e = 0; e < 8; ++e) o[e] = f2bf(W2[(size_t)(k0 + e) * HID + n]);
    } else if (f < 1024) {    // P[j][n] = W2[j][n] * M[j][n], M[j][n] = sum_i W1[i][j]*W3[n][i]
        int fi = f - 512;
        int nt = fi >> 5, ks = fi & 31;
        int n = nt * 32 + (l & 31), k0 = ks * 16 + (l >> 5) * 8;   // j = k0+e (contraction)
        float m[8] = {0.f,0.f,0.f,0.f,0.f,0.f,0.f,0.f};
        for (int i = 0; i < DIM; ++i) {
            float w3 = W3[(size_t)n * DIM + i];
#pragma unroll
            for (int e = 0; e < 8; ++e) m[e] = fmaf(W1[(size_t)i * HID + k0 + e], w3, m[e]);
        }
        unsigned short* o = ppk + (size_t)(fi * 64 + l) * 8;
#pragma unroll
        for (int e = 0; e < 8; ++e) o[e] = f2bf(W2[(size_t)(k0 + e) * HID + n] * m[e]);
    } else if (f < 1088) {    // W3 (N=64): 4 nt x 16 ks
        int fi = f - 1024;
        int nt = fi >> 4, ks = fi & 15;
        int n = nt * 16 + (l & 15), k0 = ks * 32 + (l >> 4) * 8;
        unsigned short* o = w3pk + (size_t)(fi * 64 + l) * 8;
#pragma unroll
        for (int e = 0; e < 8; ++e) o[e] = f2bf(W3[(size_t)(k0 + e) * DIM + n]);
    } else {                  // W1 (K=64): 32 nt x 2 ks
        int fi = f - 1088;
        int nt = fi >> 1, ks = fi & 1;
        int n = nt * 16 + (l & 15), k0 = ks * 32 + (l >> 4) * 8;
        unsigned short* o = w1pk + (size_t)(fi * 64 + l) * 8;
#pragma unroll
        for (int e = 0; e < 8; ++e) o[e] = f2bf(W1[(size_t)(k0 + e) * HID + n]);
    }
}

// LDS: linear [row][k] bf16, row pitch 1024B, byte ^= (row&7)<<4.
__device__ __forceinline__ int lds_addr(int row, int k) {
    return (row * 1024 + k * 2) ^ ((row & 7) << 4);
}

__global__ __launch_bounds__(NTHR, 2) void fused_main(
        const float* __restrict__ x,  const float* __restrict__ c1,
        const float* __restrict__ b2, const float* __restrict__ b3,
        const unsigned short* __restrict__ w1pk, const unsigned short* __restrict__ w2pk,
        const unsigned short* __restrict__ ppk,  const unsigned short* __restrict__ w3pk,
        float* __restrict__ out) {
    __shared__ unsigned short h1s[MB * HID];   // 32 KB
    __shared__ unsigned short d1s[MB * HID];   // 32 KB
    __shared__ unsigned short h2s[MB * HID];   // 32 KB
    __shared__ float wred[8][MB];

    const int tid = threadIdx.x;
    const int w = tid >> 6;
    const int l = tid & 63;
    const int lr = l & 15, g = l >> 4;
    const int wm = w & 1, wn = w >> 1;   // phase 1/3 decomposition: 2M x 4N
    const int s0 = blockIdx.x * MB;
    char* h1b = (char*)h1s; char* d1b = (char*)d1s; char* h2b = (char*)h2s;

    // ======== phase 1 (16x16): h1 = tanh(x @ W1 + c1), d1 = 1-h1^2 ========
    union U8 { short8 s8; unsigned short u[8]; };
    short8 ax[2];
#pragma unroll
    for (int ks = 0; ks < 2; ++ks) {
        const float* xp = x + (size_t)(s0 + wm * 16 + lr) * DIM + ks * 32 + g * 8;
        float4_ x0 = *(const float4_*)xp;
        float4_ x1 = *(const float4_*)(xp + 4);
        U8 u;
        u.u[0] = f2bf(x0.x); u.u[1] = f2bf(x0.y); u.u[2] = f2bf(x0.z); u.u[3] = f2bf(x0.w);
        u.u[4] = f2bf(x1.x); u.u[5] = f2bf(x1.y); u.u[6] = f2bf(x1.z); u.u[7] = f2bf(x1.w);
        ax[ks] = u.s8;
    }
    {
        f32x4 acc1[8];
#pragma unroll
        for (int nt = 0; nt < 8; ++nt) {
            const short8* bw = (const short8*)w1pk + (size_t)((wn * 8 + nt) * 2) * 64 + l;
            f32x4 a = {0.f, 0.f, 0.f, 0.f};
            a = __builtin_amdgcn_mfma_f32_16x16x32_bf16(ax[0], bw[0],  a, 0, 0, 0);
            a = __builtin_amdgcn_mfma_f32_16x16x32_bf16(ax[1], bw[64], a, 0, 0, 0);
            acc1[nt] = a;
        }
#pragma unroll
        for (int nt = 0; nt < 8; ++nt) {
            int c = (wn * 8 + nt) * 16 + lr;
            float c1v = c1[c];
#pragma unroll
            for (int r = 0; r < 4; ++r) {
                int row = wm * 16 + g * 4 + r;
                float h = tanh_fast(acc1[nt][r] + c1v);
                int a0 = lds_addr(row, c);
                *(unsigned short*)(h1b + a0) = f2bf(h);
                *(unsigned short*)(d1b + a0) = f2bf(fmaf(-h, h, 1.f));
            }
        }
    }
    __syncthreads();

    // ======== phase 2 (32x32x16): z2 = h1@W2+b2, srow = d1@P ========
    // wave w owns n-tiles {2w, 2w+1} (32 cols each); A-frags read once/ks, reused 2x2.
    const int nt0 = w * 2, nt1 = w * 2 + 1;
    f32x16 z0 = Z16, z1 = Z16, sv0 = Z16, sv1 = Z16;
#pragma unroll 4
    for (int ks = 0; ks < 32; ++ks) {
        int arow = l & 31;
        int ab = lds_addr(arow, ks * 16 + (l >> 5) * 8);
        short8 ah = *(const short8*)(h1b + ab);
        short8 ad = *(const short8*)(d1b + ab);
        const short8* bw = (const short8*)w2pk;
        const short8* bp = (const short8*)ppk;
        short8 bw0 = bw[(size_t)(nt0 * 32 + ks) * 64 + l];
        short8 bw1 = bw[(size_t)(nt1 * 32 + ks) * 64 + l];
        short8 bp0 = bp[(size_t)(nt0 * 32 + ks) * 64 + l];
        short8 bp1 = bp[(size_t)(nt1 * 32 + ks) * 64 + l];
        z0  = __builtin_amdgcn_mfma_f32_32x32x16_bf16(ah, bw0, z0, 0, 0, 0);
        z1  = __builtin_amdgcn_mfma_f32_32x32x16_bf16(ah, bw1, z1, 0, 0, 0);
        sv0 = __builtin_amdgcn_mfma_f32_32x32x16_bf16(ad, bp0, sv0, 0, 0, 0);
        sv1 = __builtin_amdgcn_mfma_f32_32x32x16_bf16(ad, bp1, sv1, 0, 0, 0);
    }

    // epilogue: h2 = tanh(z2), d2, div partials; store h2 to LDS
    float divp[16];
#pragma unroll
    for (int r = 0; r < 16; ++r) divp[r] = 0.f;
#pragma unroll
    for (int j = 0; j < 2; ++j) {
        f32x16 z  = j ? z1 : z0;
        f32x16 sv = j ? sv1 : sv0;
        int c = (w * 2 + j) * 32 + (l & 31);
        float b2v = b2[c];
#pragma unroll
        for (int r = 0; r < 16; ++r) {
            int row = (r & 3) + 8 * (r >> 2) + 4 * (l >> 5);   // verified C/D map
            float h2 = tanh_fast(z[r] + b2v);
            float d2 = fmaf(-h2, h2, 1.f);
            divp[r] = fmaf(sv[r], d2, divp[r]);
            *(unsigned short*)(h2b + lds_addr(row, c)) = f2bf(h2);
        }
    }

    // divergence: reduce 32 cols via shfl (within 32-lane halves), cross-wave via LDS
#pragma unroll
    for (int off = 1; off < 32; off <<= 1) {
#pragma unroll
        for (int r = 0; r < 16; ++r) divp[r] += __shfl_xor(divp[r], off, 64);
    }
    if ((l & 31) == 0) {
#pragma unroll
        for (int r = 0; r < 16; ++r) {
            int row = (r & 3) + 8 * (r >> 2) + 4 * (l >> 5);
            wred[w][row] = divp[r];
        }
    }
    __syncthreads();   // wred + h2s complete
    if (tid < MB) {
        float d = 0.f;
#pragma unroll
        for (int ww = 0; ww < 8; ++ww) d += wred[ww][tid];
        out[(size_t)BATCH * DIM + s0 + tid] = -d;
    }

    // ======== phase 3 (16x16): v = h2 @ W3 + b3 ; wave (wm,wn) -> n-tile wn ========
    {
        f32x4 acc = {0.f, 0.f, 0.f, 0.f};
        const short8* bw = (const short8*)w3pk + (size_t)(wn * 16) * 64 + l;
#pragma unroll
        for (int ks = 0; ks < 16; ++ks) {
            int ab = lds_addr(wm * 16 + lr, ks * 32 + g * 8);
            short8 a2 = *(const short8*)(h2b + ab);
            acc = __builtin_amdgcn_mfma_f32_16x16x32_bf16(a2, bw[ks * 64], acc, 0, 0, 0);
        }
        int c = wn * 16 + lr;
        float b3v = b3[c];
#pragma unroll
        for (int r = 0; r < 4; ++r)
            out[(size_t)(s0 + wm * 16 + g * 4 + r) * DIM + c] = acc[r] + b3v;
    }
}

extern "C" void kernel_launch(void* const* d_in, const int* in_sizes, int n_in,
                              void* d_out, int out_size, void* d_ws, size_t ws_size,
                              hipStream_t stream) {
    const float* t  = (const float*)d_in[0];
    const float* x  = (const float*)d_in[1];
    const float* W1 = (const float*)d_in[2];
    const float* b1 = (const float*)d_in[3];
    const float* W2 = (const float*)d_in[4];
    const float* b2 = (const float*)d_in[5];
    const float* W3 = (const float*)d_in[6];
    const float* b3 = (const float*)d_in[7];
    float* out = (float*)d_out;

    char* ws = (char*)d_ws;
    unsigned short* w2pk = (unsigned short*)ws;                          // 512 KB
    unsigned short* ppk  = (unsigned short*)(ws + (512 << 10));          // 512 KB
    unsigned short* w3pk = (unsigned short*)(ws + (1 << 20));            // 64 KB
    unsigned short* w1pk = (unsigned short*)(ws + (1 << 20) + (64 << 10)); // 64 KB
    float*          c1   = (float*)(ws + (1 << 20) + (128 << 10));       // 2 KB

    prep<<<290, 256, 0, stream>>>(t, W1, b1, W2, W3, w2pk, ppk, w3pk, w1pk, c1);
    fused_main<<<BATCH / MB, NTHR, 0, stream>>>(x, c1, b2, b3, w1pk, w2pk, ppk, w3pk, out);
}